// Round 1
// baseline (1343.214 us; speedup 1.0000x reference)
//
#include <hip/hip_runtime.h>

#define NN 100000
#define NE 1600000
#define D  64

// ---- degree histogram: deg[row[e]] += 1 ----
__global__ void k_deg(const int* __restrict__ row, float* __restrict__ deg) {
    int e = blockIdx.x * blockDim.x + threadIdx.x;
    if (e < NE) atomicAdd(&deg[row[e]], 1.0f);
}

// ---- c[o] = sum_k W3[o][k] * relu(W4[k]) ----
__global__ void k_cvec(const float* __restrict__ W3, const float* __restrict__ W4,
                       float* __restrict__ c) {
    int o = threadIdx.x;  // 64 threads
    float s = 0.f;
    for (int k = 0; k < D; ++k) {
        float w4 = W4[k];
        s += W3[o * D + k] * (w4 > 0.f ? w4 : 0.f);
    }
    c[o] = s;
}

// ---- base[i][o] = sum_k Xv[i][k]*W1[o][k] + deg[i]*c[o];  emb = relu(base) ----
__global__ __launch_bounds__(256) void k_base(
        const float* __restrict__ Xv, const float* __restrict__ W1,
        const float* __restrict__ deg, const float* __restrict__ c,
        float* __restrict__ base, float* __restrict__ emb) {
    __shared__ float w1[D][D + 1];   // +1 pad: lanes read w1[o][k], banks (o+k)%32 -> 2-way (free)
    __shared__ float cs[D];
    __shared__ float xv[4][D];
    int tid = threadIdx.x;
    int o = tid & 63;
    int g = tid >> 6;                 // 4 nodes per block
    for (int i = tid; i < D * D; i += 256) w1[i >> 6][i & 63] = W1[i];
    if (tid < D) cs[tid] = c[tid];
    int node = blockIdx.x * 4 + g;
    if (node < NN) xv[g][o] = Xv[node * D + o];
    __syncthreads();
    if (node < NN) {
        float s = 0.f;
        #pragma unroll
        for (int k = 0; k < D; ++k) s += xv[g][k] * w1[o][k];
        s += deg[node] * cs[o];
        base[node * D + o] = s;
        emb[node * D + o] = s > 0.f ? s : 0.f;
    }
}

// ---- neigh[row[e]][o] += emb[col[e]][o]  (one 64-lane group per edge, grid-stride) ----
__global__ __launch_bounds__(256) void k_gather(
        const int* __restrict__ row, const int* __restrict__ col,
        const float* __restrict__ emb, float* __restrict__ neigh) {
    int gid = blockIdx.x * blockDim.x + threadIdx.x;
    int group = gid >> 6;
    int o = gid & 63;
    int ngroups = (gridDim.x * blockDim.x) >> 6;
    for (int e = group; e < NE; e += ngroups) {
        int r = row[e];
        int cc = col[e];
        atomicAdd(&neigh[(size_t)r * D + o], emb[(size_t)cc * D + o]);
    }
}

// ---- emb[i][o] = relu(base[i][o] + sum_k neigh[i][k]*W2[o][k]) ----
__global__ __launch_bounds__(256) void k_update(
        const float* __restrict__ base, const float* __restrict__ neigh,
        const float* __restrict__ W2, float* __restrict__ emb) {
    __shared__ float w2[D][D + 1];
    __shared__ float nb[4][D];
    int tid = threadIdx.x;
    int o = tid & 63;
    int g = tid >> 6;
    for (int i = tid; i < D * D; i += 256) w2[i >> 6][i & 63] = W2[i];
    int node = blockIdx.x * 4 + g;
    if (node < NN) nb[g][o] = neigh[node * D + o];
    __syncthreads();
    if (node < NN) {
        float s = base[node * D + o];
        #pragma unroll
        for (int k = 0; k < D; ++k) s += nb[g][k] * w2[o][k];
        emb[node * D + o] = s > 0.f ? s : 0.f;
    }
}

extern "C" void kernel_launch(void* const* d_in, const int* in_sizes, int n_in,
                              void* d_out, int out_size, void* d_ws, size_t ws_size,
                              hipStream_t stream) {
    const float* Xv = (const float*)d_in[0];
    const int*   ei = (const int*)d_in[1];   // (2, NE) int32
    const float* W1 = (const float*)d_in[2];
    const float* W2 = (const float*)d_in[3];
    const float* W3 = (const float*)d_in[4];
    const float* W4 = (const float*)d_in[5];
    float* emb = (float*)d_out;

    char* ws = (char*)d_ws;
    float* base  = (float*)ws;                                    // NN*D floats
    float* neigh = (float*)(ws + (size_t)NN * D * 4);             // NN*D floats
    float* deg   = (float*)(ws + (size_t)2 * NN * D * 4);         // NN floats
    float* cvec  = (float*)(ws + (size_t)2 * NN * D * 4 + (size_t)NN * 4); // D floats

    const int* row = ei;
    const int* col = ei + NE;

    hipMemsetAsync(deg, 0, NN * sizeof(float), stream);
    k_deg<<<(NE + 255) / 256, 256, 0, stream>>>(row, deg);
    k_cvec<<<1, 64, 0, stream>>>(W3, W4, cvec);
    // step 1: emb = relu(base)  (neigh is zero on the first reference iteration)
    k_base<<<(NN + 3) / 4, 256, 0, stream>>>(Xv, W1, deg, cvec, base, emb);
    // steps 2..4
    for (int t = 0; t < 3; ++t) {
        hipMemsetAsync(neigh, 0, (size_t)NN * D * sizeof(float), stream);
        k_gather<<<8192, 256, 0, stream>>>(row, col, emb, neigh);
        k_update<<<(NN + 3) / 4, 256, 0, stream>>>(base, neigh, W2, emb);
    }
}

// Round 2
// 548.120 us; speedup vs baseline: 2.4506x; 2.4506x over previous
//
#include <hip/hip_runtime.h>

#define NN 100000
#define NE 1600000
#define D  64
#define SCAN_BLK 256
#define NB_SCAN ((NN + SCAN_BLK - 1) / SCAN_BLK)   // 391

__device__ __forceinline__ float bf2f(unsigned short x) {
    return __uint_as_float(((unsigned)x) << 16);
}
__device__ __forceinline__ unsigned short f2bf(float f) {  // RNE
    unsigned u = __float_as_uint(f);
    return (unsigned short)((u + 0x7fff + ((u >> 16) & 1)) >> 16);
}

// ---- edge histogram: cnt[row[e]] += 1 ----
__global__ void k_count(const int* __restrict__ row, int* __restrict__ cnt) {
    int e = blockIdx.x * blockDim.x + threadIdx.x;
    if (e < NE) atomicAdd(&cnt[row[e]], 1);
}

// ---- scan pass 1: per-block sums of cnt ----
__global__ void k_scan1(const int* __restrict__ cnt, int* __restrict__ bsum) {
    __shared__ int sm[SCAN_BLK];
    int i = blockIdx.x * SCAN_BLK + threadIdx.x;
    sm[threadIdx.x] = (i < NN) ? cnt[i] : 0;
    __syncthreads();
    for (int s = SCAN_BLK / 2; s > 0; s >>= 1) {
        if (threadIdx.x < s) sm[threadIdx.x] += sm[threadIdx.x + s];
        __syncthreads();
    }
    if (threadIdx.x == 0) bsum[blockIdx.x] = sm[0];
}

// ---- scan pass 2: exclusive scan of block sums (nb <= 512), one block ----
__global__ void k_scan2(int* __restrict__ bsum, int nb) {
    __shared__ int sm[512];
    int t = threadIdx.x;
    int v = (t < nb) ? bsum[t] : 0;
    sm[t] = v;
    __syncthreads();
    for (int s = 1; s < 512; s <<= 1) {
        int add = (t >= s) ? sm[t - s] : 0;
        __syncthreads();
        sm[t] += add;
        __syncthreads();
    }
    if (t < nb) bsum[t] = sm[t] - v;   // exclusive
}

// ---- scan pass 3: per-block exclusive scan + block offset -> cursor (=row start) ----
__global__ void k_scan3(const int* __restrict__ cnt, const int* __restrict__ bsum,
                        int* __restrict__ cursor) {
    __shared__ int sm[SCAN_BLK];
    int i = blockIdx.x * SCAN_BLK + threadIdx.x;
    int v = (i < NN) ? cnt[i] : 0;
    sm[threadIdx.x] = v;
    __syncthreads();
    for (int s = 1; s < SCAN_BLK; s <<= 1) {
        int add = (threadIdx.x >= s) ? sm[threadIdx.x - s] : 0;
        __syncthreads();
        sm[threadIdx.x] += add;
        __syncthreads();
    }
    if (i < NN) cursor[i] = bsum[blockIdx.x] + sm[threadIdx.x] - v;
}

// ---- scatter edges into CSR: csr_col[cursor[r]++] = col[e] ----
// After this kernel cursor[i] == row-end offset (start = end - cnt[i]).
__global__ void k_scatter(const int* __restrict__ row, const int* __restrict__ col,
                          int* __restrict__ cursor, int* __restrict__ csr_col) {
    int e = blockIdx.x * blockDim.x + threadIdx.x;
    if (e < NE) {
        int p = atomicAdd(&cursor[row[e]], 1);
        csr_col[p] = col[e];
    }
}

// ---- c[o] = sum_k W3[o][k] * relu(W4[k]) ----
__global__ void k_cvec(const float* __restrict__ W3, const float* __restrict__ W4,
                       float* __restrict__ c) {
    int o = threadIdx.x;  // 64 threads
    float s = 0.f;
    for (int k = 0; k < D; ++k) {
        float w4 = W4[k];
        s += W3[o * D + k] * (w4 > 0.f ? w4 : 0.f);
    }
    c[o] = s;
}

// ---- base = Xv@W1.T + deg*c ; emb = relu(base) ----
__global__ __launch_bounds__(256) void k_base(
        const float* __restrict__ Xv, const float* __restrict__ W1,
        const int* __restrict__ cnt, const float* __restrict__ c,
        float* __restrict__ base, float* __restrict__ emb) {
    __shared__ float w1[D][D + 1];
    __shared__ float cs[D];
    __shared__ float xv[4][D];
    int tid = threadIdx.x;
    int o = tid & 63;
    int g = tid >> 6;
    for (int i = tid; i < D * D; i += 256) w1[i >> 6][i & 63] = W1[i];
    if (tid < D) cs[tid] = c[tid];
    int node = blockIdx.x * 4 + g;     // NN % 4 == 0, always valid
    xv[g][o] = Xv[(size_t)node * D + o];
    __syncthreads();
    float s = 0.f;
    #pragma unroll
    for (int k = 0; k < D; ++k) s += xv[g][k] * w1[o][k];
    s += (float)cnt[node] * cs[o];
    base[(size_t)node * D + o] = s;
    emb[(size_t)node * D + o] = s > 0.f ? s : 0.f;
}

// ---- h = emb @ W2.T  (bf16 output) ----
__global__ __launch_bounds__(256) void k_h(
        const float* __restrict__ emb, const float* __restrict__ W2,
        unsigned short* __restrict__ h) {
    __shared__ float w2[D][D + 1];
    __shared__ float nb[4][D];
    int tid = threadIdx.x;
    for (int i = tid; i < D * D; i += 256) w2[i >> 6][i & 63] = W2[i];
    int wave = tid >> 6, o = tid & 63;
    __syncthreads();
    for (int it = blockIdx.x; it < NN / 4; it += gridDim.x) {
        int node = it * 4 + wave;
        nb[wave][o] = emb[(size_t)node * D + o];
        __syncthreads();
        float s = 0.f;
        #pragma unroll
        for (int k = 0; k < D; ++k) s += nb[wave][k] * w2[o][k];
        h[(size_t)node * D + o] = f2bf(s);
        __syncthreads();
    }
}

// ---- emb[i] = relu(base[i] + sum_{j in N(i)} h[csr_col[j]])  (pull, no atomics) ----
__global__ __launch_bounds__(256) void k_pull(
        const int* __restrict__ end_ptr, const int* __restrict__ cnt,
        const int* __restrict__ csr_col, const unsigned short* __restrict__ h,
        const float* __restrict__ base, float* __restrict__ emb) {
    int tid = threadIdx.x;
    int wave = tid >> 6, lane = tid & 63;
    int q = lane >> 4, l = lane & 15;          // quad q handles edges start+q, +4, ...
    for (int it = blockIdx.x; it < NN / 4; it += gridDim.x) {
        int node = it * 4 + wave;
        int end = end_ptr[node];
        int start = end - cnt[node];
        float4 acc = {0.f, 0.f, 0.f, 0.f};
        for (int j = start + q; j < end; j += 4) {
            int cidx = csr_col[j];
            ushort4 v = *((const ushort4*)(h + (size_t)cidx * D) + l);  // 4 bf16 = 8B
            acc.x += bf2f(v.x);
            acc.y += bf2f(v.y);
            acc.z += bf2f(v.z);
            acc.w += bf2f(v.w);
        }
        // reduce across the 4 quads (lanes l, l+16, l+32, l+48)
        #pragma unroll
        for (int m = 16; m < 64; m <<= 1) {
            acc.x += __shfl_xor(acc.x, m);
            acc.y += __shfl_xor(acc.y, m);
            acc.z += __shfl_xor(acc.z, m);
            acc.w += __shfl_xor(acc.w, m);
        }
        if (q == 0) {
            float4 b = *((const float4*)(base + (size_t)node * D) + l);
            float4 r;
            r.x = fmaxf(b.x + acc.x, 0.f);
            r.y = fmaxf(b.y + acc.y, 0.f);
            r.z = fmaxf(b.z + acc.z, 0.f);
            r.w = fmaxf(b.w + acc.w, 0.f);
            *((float4*)(emb + (size_t)node * D) + l) = r;
        }
    }
}

extern "C" void kernel_launch(void* const* d_in, const int* in_sizes, int n_in,
                              void* d_out, int out_size, void* d_ws, size_t ws_size,
                              hipStream_t stream) {
    const float* Xv = (const float*)d_in[0];
    const int*   ei = (const int*)d_in[1];
    const float* W1 = (const float*)d_in[2];
    const float* W2 = (const float*)d_in[3];
    const float* W3 = (const float*)d_in[4];
    const float* W4 = (const float*)d_in[5];
    float* emb = (float*)d_out;

    char* ws = (char*)d_ws;
    size_t off = 0;
    float* base = (float*)(ws + off);           off += (size_t)NN * D * 4;   // 25.6 MB
    unsigned short* h = (unsigned short*)(ws + off); off += (size_t)NN * D * 2; // 12.8 MB
    int* csr_col = (int*)(ws + off);            off += (size_t)NE * 4;       // 6.4 MB
    int* cnt     = (int*)(ws + off);            off += (size_t)NN * 4;
    int* cursor  = (int*)(ws + off);            off += (size_t)NN * 4;
    int* bsum    = (int*)(ws + off);            off += 512 * 4;
    float* cvec  = (float*)(ws + off);          off += D * 4;

    const int* row = ei;
    const int* col = ei + NE;

    // ---- CSR build (once per call) ----
    hipMemsetAsync(cnt, 0, NN * sizeof(int), stream);
    k_count<<<(NE + 255) / 256, 256, 0, stream>>>(row, cnt);
    k_scan1<<<NB_SCAN, SCAN_BLK, 0, stream>>>(cnt, bsum);
    k_scan2<<<1, 512, 0, stream>>>(bsum, NB_SCAN);
    k_scan3<<<NB_SCAN, SCAN_BLK, 0, stream>>>(cnt, bsum, cursor);
    k_scatter<<<(NE + 255) / 256, 256, 0, stream>>>(row, col, cursor, csr_col);
    // cursor now holds row END offsets.

    // ---- base, emb1 = relu(base) ----
    k_cvec<<<1, 64, 0, stream>>>(W3, W4, cvec);
    k_base<<<NN / 4, 256, 0, stream>>>(Xv, W1, cnt, cvec, base, emb);

    // ---- 3 remaining message-passing steps ----
    for (int t = 0; t < 3; ++t) {
        k_h<<<2048, 256, 0, stream>>>(emb, W2, h);
        k_pull<<<2048, 256, 0, stream>>>(cursor, cnt, csr_col, h, base, emb);
    }
}

// Round 3
// 429.655 us; speedup vs baseline: 3.1263x; 1.2757x over previous
//
#include <hip/hip_runtime.h>

#define NN 100000
#define NE 1600000
#define D  64
#define SCAN_BLK 256
#define NB_SCAN ((NN + SCAN_BLK - 1) / SCAN_BLK)   // 391

typedef __attribute__((ext_vector_type(8))) short short8v;
typedef __attribute__((ext_vector_type(8))) unsigned short ushort8v;
typedef __attribute__((ext_vector_type(4))) float f32x4;

__device__ __forceinline__ float bf2f(unsigned short x) {
    return __uint_as_float(((unsigned)x) << 16);
}
__device__ __forceinline__ unsigned short f2bf(float f) {  // RNE
    unsigned u = __float_as_uint(f);
    return (unsigned short)((u + 0x7fff + ((u >> 16) & 1)) >> 16);
}

// ---- edge histogram: cnt[row[e]] += 1, 4 edges/thread ----
__global__ void k_count(const int* __restrict__ row, int* __restrict__ cnt) {
    int i = blockIdx.x * blockDim.x + threadIdx.x;
    if (i < NE / 4) {
        int4 r = ((const int4*)row)[i];
        atomicAdd(&cnt[r.x], 1);
        atomicAdd(&cnt[r.y], 1);
        atomicAdd(&cnt[r.z], 1);
        atomicAdd(&cnt[r.w], 1);
    }
}

// ---- scan pass 1: per-block sums of cnt ----
__global__ void k_scan1(const int* __restrict__ cnt, int* __restrict__ bsum) {
    __shared__ int sm[SCAN_BLK];
    int i = blockIdx.x * SCAN_BLK + threadIdx.x;
    sm[threadIdx.x] = (i < NN) ? cnt[i] : 0;
    __syncthreads();
    for (int s = SCAN_BLK / 2; s > 0; s >>= 1) {
        if (threadIdx.x < s) sm[threadIdx.x] += sm[threadIdx.x + s];
        __syncthreads();
    }
    if (threadIdx.x == 0) bsum[blockIdx.x] = sm[0];
}

// ---- scan pass 2: exclusive scan of block sums (nb <= 512), one block ----
__global__ void k_scan2(int* __restrict__ bsum, int nb) {
    __shared__ int sm[512];
    int t = threadIdx.x;
    int v = (t < nb) ? bsum[t] : 0;
    sm[t] = v;
    __syncthreads();
    for (int s = 1; s < 512; s <<= 1) {
        int add = (t >= s) ? sm[t - s] : 0;
        __syncthreads();
        sm[t] += add;
        __syncthreads();
    }
    if (t < nb) bsum[t] = sm[t] - v;   // exclusive
}

// ---- scan pass 3: per-block exclusive scan + block offset -> cursor (=row start) ----
__global__ void k_scan3(const int* __restrict__ cnt, const int* __restrict__ bsum,
                        int* __restrict__ cursor) {
    __shared__ int sm[SCAN_BLK];
    int i = blockIdx.x * SCAN_BLK + threadIdx.x;
    int v = (i < NN) ? cnt[i] : 0;
    sm[threadIdx.x] = v;
    __syncthreads();
    for (int s = 1; s < SCAN_BLK; s <<= 1) {
        int add = (threadIdx.x >= s) ? sm[threadIdx.x - s] : 0;
        __syncthreads();
        sm[threadIdx.x] += add;
        __syncthreads();
    }
    if (i < NN) cursor[i] = bsum[blockIdx.x] + sm[threadIdx.x] - v;
}

// ---- scatter edges into CSR; afterwards cursor[i] == row END offset ----
__global__ void k_scatter(const int* __restrict__ row, const int* __restrict__ col,
                          int* __restrict__ cursor, int* __restrict__ csr_col) {
    int e = blockIdx.x * blockDim.x + threadIdx.x;
    if (e < NE) {
        int p = atomicAdd(&cursor[row[e]], 1);
        csr_col[p] = col[e];
    }
}

// ---- c[o] = sum_k W3[o][k] * relu(W4[k]) ----
__global__ void k_cvec(const float* __restrict__ W3, const float* __restrict__ W4,
                       float* __restrict__ c) {
    int o = threadIdx.x;  // 64 threads
    float s = 0.f;
    for (int k = 0; k < D; ++k) {
        float w4 = W4[k];
        s += W3[o * D + k] * (w4 > 0.f ? w4 : 0.f);
    }
    c[o] = s;
}

// ---- W2 fp32 -> bf16 ----
__global__ void k_w2bf(const float* __restrict__ W2, unsigned short* __restrict__ w2b) {
    int i = blockIdx.x * 256 + threadIdx.x;
    if (i < D * D) w2b[i] = f2bf(W2[i]);
}

// ---- base = Xv@W1.T + deg*c ; emb = relu(base) ----
__global__ __launch_bounds__(256) void k_base(
        const float* __restrict__ Xv, const float* __restrict__ W1,
        const int* __restrict__ cnt, const float* __restrict__ c,
        float* __restrict__ base, float* __restrict__ emb) {
    __shared__ float w1[D][D + 1];
    __shared__ float cs[D];
    __shared__ float xv[4][D];
    int tid = threadIdx.x;
    int o = tid & 63;
    int g = tid >> 6;
    for (int i = tid; i < D * D; i += 256) w1[i >> 6][i & 63] = W1[i];
    if (tid < D) cs[tid] = c[tid];
    int node = blockIdx.x * 4 + g;     // NN % 4 == 0
    xv[g][o] = Xv[(size_t)node * D + o];
    __syncthreads();
    float s = 0.f;
    #pragma unroll
    for (int k = 0; k < D; ++k) s += xv[g][k] * w1[o][k];
    s += (float)cnt[node] * cs[o];
    base[(size_t)node * D + o] = s;
    emb[(size_t)node * D + o] = s > 0.f ? s : 0.f;
}

// ---- h = (bf16)emb @ W2bf.T via MFMA, 16 nodes per wave ----
__global__ __launch_bounds__(256) void k_h(
        const float* __restrict__ emb, const unsigned short* __restrict__ w2b,
        unsigned short* __restrict__ h) {
    int wid = blockIdx.x * 4 + (threadIdx.x >> 6);
    int lane = threadIdx.x & 63;
    int m0 = wid * 16;
    if (m0 >= NN) return;                 // NN/16 = 6250 waves
    int r = lane & 15, half = lane >> 4;
    // A frags: lane holds emb[m0+r][k], k = (half*8 .. +7) and (+32)
    const float* arow = emb + (size_t)(m0 + r) * D + half * 8;
    f32x4 af0a = *(const f32x4*)(arow);
    f32x4 af0b = *(const f32x4*)(arow + 4);
    f32x4 af1a = *(const f32x4*)(arow + 32);
    f32x4 af1b = *(const f32x4*)(arow + 36);
    short8v a0, a1;
    #pragma unroll
    for (int j = 0; j < 4; ++j) {
        a0[j]     = (short)f2bf(af0a[j]);
        a0[j + 4] = (short)f2bf(af0b[j]);
        a1[j]     = (short)f2bf(af1a[j]);
        a1[j + 4] = (short)f2bf(af1b[j]);
    }
    #pragma unroll
    for (int t = 0; t < 4; ++t) {
        // B frag: lane holds B[k][n=t*16+r] = W2[n][k], k as in A
        short8v b0 = *(const short8v*)(w2b + (size_t)(t * 16 + r) * D + half * 8);
        short8v b1 = *(const short8v*)(w2b + (size_t)(t * 16 + r) * D + 32 + half * 8);
        f32x4 cacc = {0.f, 0.f, 0.f, 0.f};
        cacc = __builtin_amdgcn_mfma_f32_16x16x32_bf16(a0, b0, cacc, 0, 0, 0);
        cacc = __builtin_amdgcn_mfma_f32_16x16x32_bf16(a1, b1, cacc, 0, 0, 0);
        // C/D: row = half*4 + q (node), col = r (out ch within tile t)  [m89-verified]
        #pragma unroll
        for (int q = 0; q < 4; ++q)
            h[(size_t)(m0 + half * 4 + q) * D + t * 16 + r] = f2bf(cacc[q]);
    }
}

// ---- emb[i] = relu(base[i] + sum_{j in N(i)} h[csr_col[j]]) ; 8 edges in flight ----
__global__ __launch_bounds__(256) void k_pull(
        const int* __restrict__ end_ptr, const int* __restrict__ cnt,
        const int* __restrict__ csr_col, const unsigned short* __restrict__ h,
        const float* __restrict__ base, float* __restrict__ emb) {
    int tid = threadIdx.x;
    int wave = tid >> 6, lane = tid & 63;
    int g = lane >> 3, l = lane & 7;       // group g: edges start+g, +8, ...; lane-in-group l: ch l*8..+7
    for (int it = blockIdx.x; it < NN / 4; it += gridDim.x) {
        int node = it * 4 + wave;
        int end = end_ptr[node];
        int start = end - cnt[node];
        float acc[8] = {0.f, 0.f, 0.f, 0.f, 0.f, 0.f, 0.f, 0.f};
        for (int j = start + g; j < end; j += 8) {
            int cidx = csr_col[j];
            ushort8v v = *((const ushort8v*)(h + (size_t)cidx * D) + l);  // 16B
            #pragma unroll
            for (int u = 0; u < 8; ++u) acc[u] += bf2f(v[u]);
        }
        // butterfly over the 8 groups (lane bits 3,4,5) — every lane ends with the sum
        #pragma unroll
        for (int m = 8; m < 64; m <<= 1) {
            #pragma unroll
            for (int u = 0; u < 8; ++u) acc[u] += __shfl_xor(acc[u], m);
        }
        if (g < 2) {     // 16 lanes issue one coalesced 256B row store
            int off = l * 8 + g * 4;
            f32x4 lo = {acc[0], acc[1], acc[2], acc[3]};
            f32x4 hi = {acc[4], acc[5], acc[6], acc[7]};
            f32x4 b = *(const f32x4*)(base + (size_t)node * D + off);
            f32x4 rr;
            #pragma unroll
            for (int u = 0; u < 4; ++u) {
                float a = (g == 1) ? hi[u] : lo[u];
                rr[u] = fmaxf(b[u] + a, 0.f);
            }
            *(f32x4*)(emb + (size_t)node * D + off) = rr;
        }
    }
}

extern "C" void kernel_launch(void* const* d_in, const int* in_sizes, int n_in,
                              void* d_out, int out_size, void* d_ws, size_t ws_size,
                              hipStream_t stream) {
    const float* Xv = (const float*)d_in[0];
    const int*   ei = (const int*)d_in[1];
    const float* W1 = (const float*)d_in[2];
    const float* W2 = (const float*)d_in[3];
    const float* W3 = (const float*)d_in[4];
    const float* W4 = (const float*)d_in[5];
    float* emb = (float*)d_out;

    char* ws = (char*)d_ws;
    size_t off = 0;
    float* base = (float*)(ws + off);                 off += (size_t)NN * D * 4;  // 25.6 MB
    unsigned short* h = (unsigned short*)(ws + off);  off += (size_t)NN * D * 2;  // 12.8 MB
    int* csr_col = (int*)(ws + off);                  off += (size_t)NE * 4;      // 6.4 MB
    int* cnt     = (int*)(ws + off);                  off += (size_t)NN * 4;
    int* cursor  = (int*)(ws + off);                  off += (size_t)NN * 4;
    int* bsum    = (int*)(ws + off);                  off += 512 * 4;
    float* cvec  = (float*)(ws + off);                off += D * 4;
    unsigned short* w2b = (unsigned short*)(ws + off); off += D * D * 2;

    const int* row = ei;
    const int* col = ei + NE;

    // ---- CSR build ----
    hipMemsetAsync(cnt, 0, NN * sizeof(int), stream);
    k_count<<<(NE / 4 + 255) / 256, 256, 0, stream>>>(row, cnt);
    k_scan1<<<NB_SCAN, SCAN_BLK, 0, stream>>>(cnt, bsum);
    k_scan2<<<1, 512, 0, stream>>>(bsum, NB_SCAN);
    k_scan3<<<NB_SCAN, SCAN_BLK, 0, stream>>>(cnt, bsum, cursor);
    k_scatter<<<(NE + 255) / 256, 256, 0, stream>>>(row, col, cursor, csr_col);

    // ---- base, emb1 = relu(base) ----
    k_cvec<<<1, 64, 0, stream>>>(W3, W4, cvec);
    k_w2bf<<<16, 256, 0, stream>>>(W2, w2b);
    k_base<<<NN / 4, 256, 0, stream>>>(Xv, W1, cnt, cvec, base, emb);

    // ---- 3 remaining message-passing steps ----
    for (int t = 0; t < 3; ++t) {
        k_h<<<(NN / 16 + 3) / 4, 256, 0, stream>>>(emb, w2b, h);
        k_pull<<<2048, 256, 0, stream>>>(cursor, cnt, csr_col, h, base, emb);
    }
}

// Round 4
// 282.773 us; speedup vs baseline: 4.7502x; 1.5194x over previous
//
#include <hip/hip_runtime.h>

#define NN 100000
#define NE 1600000
#define D  64
#define BSH 8                                  // bucket shift: 256 nodes/bucket
#define NBKT ((NN + 255) >> BSH)               // 391
#define NBLK_E ((NE / 4 + 1023) / 1024)        // 391 blocks, 1024 int4s each

typedef __attribute__((ext_vector_type(8))) short short8v;
typedef __attribute__((ext_vector_type(8))) unsigned short ushort8v;
typedef __attribute__((ext_vector_type(4))) unsigned short ushort4v;
typedef __attribute__((ext_vector_type(4))) float f32x4;

__device__ __forceinline__ float bf2f(unsigned short x) {
    return __uint_as_float(((unsigned)x) << 16);
}
__device__ __forceinline__ unsigned short f2bf(float f) {  // RNE
    unsigned u = __float_as_uint(f);
    return (unsigned short)((u + 0x7fff + ((u >> 16) & 1)) >> 16);
}

// ---- pass A: global bucket histogram (LDS-staged) ----
__global__ __launch_bounds__(256) void k_hist(const int* __restrict__ row,
                                              int* __restrict__ ghist) {
    __shared__ int h[NBKT];
    int tid = threadIdx.x;
    for (int i = tid; i < NBKT; i += 256) h[i] = 0;
    __syncthreads();
    int base4 = blockIdx.x * 1024;
    #pragma unroll
    for (int k = 0; k < 4; ++k) {
        int i4 = base4 + k * 256 + tid;
        if (i4 < NE / 4) {
            int4 r = ((const int4*)row)[i4];
            atomicAdd(&h[r.x >> BSH], 1);
            atomicAdd(&h[r.y >> BSH], 1);
            atomicAdd(&h[r.z >> BSH], 1);
            atomicAdd(&h[r.w >> BSH], 1);
        }
    }
    __syncthreads();
    for (int i = tid; i < NBKT; i += 256) if (h[i]) atomicAdd(&ghist[i], h[i]);
}

// ---- pass B: exclusive scan of 391 bucket counts (1 block, Hillis over 512) ----
__global__ __launch_bounds__(256) void k_bscan(const int* __restrict__ ghist,
                                               int* __restrict__ bbase,
                                               int* __restrict__ bcur) {
    __shared__ int sc[2][512];
    int t = threadIdx.x;
    int cur = 0;
    #pragma unroll
    for (int k = 0; k < 2; ++k) {
        int i = t + k * 256;
        sc[0][i] = (i < NBKT) ? ghist[i] : 0;
    }
    __syncthreads();
    for (int s = 1; s < 512; s <<= 1) {
        #pragma unroll
        for (int k = 0; k < 2; ++k) {
            int i = t + k * 256;
            sc[cur ^ 1][i] = sc[cur][i] + ((i >= s) ? sc[cur][i - s] : 0);
        }
        cur ^= 1;
        __syncthreads();
    }
    #pragma unroll
    for (int k = 0; k < 2; ++k) {
        int i = t + k * 256;
        if (i < NBKT) {
            int b = (i == 0) ? 0 : sc[cur][i - 1];
            bbase[i] = b;
            bcur[i] = b;
        } else if (i == NBKT) {
            bbase[NBKT] = sc[cur][NBKT - 1];   // = NE
        }
    }
}

// ---- pass C: bucket-sort edges into packed u32 (lrow<<17 | col) ----
__global__ __launch_bounds__(256) void k_bucket(const int* __restrict__ row,
                                                const int* __restrict__ col,
                                                int* __restrict__ bcur,
                                                unsigned* __restrict__ sorted) {
    __shared__ int hist[NBKT];
    __shared__ int bbase_s[NBKT];
    int tid = threadIdx.x;
    for (int i = tid; i < NBKT; i += 256) hist[i] = 0;
    __syncthreads();
    int base4 = blockIdx.x * 1024;
    int4 r4[4], c4[4];
    int rank[16];
    bool valid[4];
    #pragma unroll
    for (int k = 0; k < 4; ++k) {
        int i4 = base4 + k * 256 + tid;
        valid[k] = (i4 < NE / 4);
        if (valid[k]) {
            r4[k] = ((const int4*)row)[i4];
            c4[k] = ((const int4*)col)[i4];
            rank[k * 4 + 0] = atomicAdd(&hist[r4[k].x >> BSH], 1);
            rank[k * 4 + 1] = atomicAdd(&hist[r4[k].y >> BSH], 1);
            rank[k * 4 + 2] = atomicAdd(&hist[r4[k].z >> BSH], 1);
            rank[k * 4 + 3] = atomicAdd(&hist[r4[k].w >> BSH], 1);
        }
    }
    __syncthreads();
    for (int i = tid; i < NBKT; i += 256)
        bbase_s[i] = hist[i] ? atomicAdd(&bcur[i], hist[i]) : 0;
    __syncthreads();
    #pragma unroll
    for (int k = 0; k < 4; ++k) {
        if (valid[k]) {
            int rr[4] = {r4[k].x, r4[k].y, r4[k].z, r4[k].w};
            int cc[4] = {c4[k].x, c4[k].y, c4[k].z, c4[k].w};
            #pragma unroll
            for (int j = 0; j < 4; ++j) {
                int b = rr[j] >> BSH;
                unsigned pk = ((unsigned)(rr[j] & 255) << 17) | (unsigned)cc[j];
                sorted[bbase_s[b] + rank[k * 4 + j]] = pk;
            }
        }
    }
}

// ---- pass D: per-bucket fine CSR (LDS count -> scan -> scatter) ----
__global__ __launch_bounds__(256) void k_fine(const unsigned* __restrict__ sorted,
                                              const int* __restrict__ bbase,
                                              int* __restrict__ csr_col,
                                              int* __restrict__ cnt_g,
                                              int* __restrict__ end_g) {
    __shared__ int cnt_s[256];
    __shared__ int cur_s[256];
    __shared__ int sc[2][256];
    int b = blockIdx.x;
    int tid = threadIdx.x;
    int s0 = bbase[b], e0 = bbase[b + 1];
    cnt_s[tid] = 0;
    __syncthreads();
    for (int i = s0 + tid; i < e0; i += 256)
        atomicAdd(&cnt_s[sorted[i] >> 17], 1);
    __syncthreads();
    int cur = 0;
    sc[0][tid] = cnt_s[tid];
    __syncthreads();
    for (int s = 1; s < 256; s <<= 1) {
        sc[cur ^ 1][tid] = sc[cur][tid] + ((tid >= s) ? sc[cur][tid - s] : 0);
        cur ^= 1;
        __syncthreads();
    }
    int incl = sc[cur][tid];
    cur_s[tid] = incl - cnt_s[tid];           // exclusive offset
    int nb = NN - b * 256;
    nb = nb > 256 ? 256 : nb;
    if (tid < nb) {
        int node = b * 256 + tid;
        cnt_g[node] = cnt_s[tid];
        end_g[node] = s0 + incl;
    }
    __syncthreads();
    for (int i = s0 + tid; i < e0; i += 256) {
        unsigned u = sorted[i];
        int p = atomicAdd(&cur_s[u >> 17], 1);
        csr_col[s0 + p] = (int)(u & 0x1FFFFu);
    }
}

// ---- c[o] = sum_k W3[o][k] * relu(W4[k]) ----
__global__ void k_cvec(const float* __restrict__ W3, const float* __restrict__ W4,
                       float* __restrict__ c) {
    int o = threadIdx.x;  // 64 threads
    float s = 0.f;
    for (int k = 0; k < D; ++k) {
        float w4 = W4[k];
        s += W3[o * D + k] * (w4 > 0.f ? w4 : 0.f);
    }
    c[o] = s;
}

// ---- W2 fp32 -> bf16 ----
__global__ void k_w2bf(const float* __restrict__ W2, unsigned short* __restrict__ w2b) {
    int i = blockIdx.x * 256 + threadIdx.x;
    if (i < D * D) w2b[i] = f2bf(W2[i]);
}

// ---- base = Xv@W1.T + deg*c (fp32); emb_bf = relu(base) in bf16 ----
__global__ __launch_bounds__(256) void k_base(
        const float* __restrict__ Xv, const float* __restrict__ W1,
        const int* __restrict__ cnt, const float* __restrict__ c,
        float* __restrict__ base, unsigned short* __restrict__ emb_bf) {
    __shared__ float w1[D][D + 1];
    __shared__ float cs[D];
    __shared__ float xv[4][D];
    int tid = threadIdx.x;
    int o = tid & 63;
    int g = tid >> 6;
    for (int i = tid; i < D * D; i += 256) w1[i >> 6][i & 63] = W1[i];
    if (tid < D) cs[tid] = c[tid];
    int node = blockIdx.x * 4 + g;     // NN % 4 == 0
    xv[g][o] = Xv[(size_t)node * D + o];
    __syncthreads();
    float s = 0.f;
    #pragma unroll
    for (int k = 0; k < D; ++k) s += xv[g][k] * w1[o][k];
    s += (float)cnt[node] * cs[o];
    base[(size_t)node * D + o] = s;
    emb_bf[(size_t)node * D + o] = f2bf(s > 0.f ? s : 0.f);
}

// ---- h = emb_bf @ W2bf.T via MFMA, 16 nodes per wave ----
__global__ __launch_bounds__(256) void k_h(
        const unsigned short* __restrict__ emb_bf, const unsigned short* __restrict__ w2b,
        unsigned short* __restrict__ h) {
    int wid = blockIdx.x * 4 + (threadIdx.x >> 6);
    int lane = threadIdx.x & 63;
    int m0 = wid * 16;
    if (m0 >= NN) return;                 // NN/16 = 6250 waves
    int r = lane & 15, half = lane >> 4;
    // A frags: lane holds emb[m0+r][k], k = half*8..+7 and +32 (same k-map as B; any
    // k-permutation error cancels between A and B)
    const unsigned short* arow = emb_bf + (size_t)(m0 + r) * D + half * 8;
    short8v a0 = *(const short8v*)(arow);
    short8v a1 = *(const short8v*)(arow + 32);
    #pragma unroll
    for (int t = 0; t < 4; ++t) {
        short8v b0 = *(const short8v*)(w2b + (size_t)(t * 16 + r) * D + half * 8);
        short8v b1 = *(const short8v*)(w2b + (size_t)(t * 16 + r) * D + 32 + half * 8);
        f32x4 cacc = {0.f, 0.f, 0.f, 0.f};
        cacc = __builtin_amdgcn_mfma_f32_16x16x32_bf16(a0, b0, cacc, 0, 0, 0);
        cacc = __builtin_amdgcn_mfma_f32_16x16x32_bf16(a1, b1, cacc, 0, 0, 0);
        // C/D: row = half*4 + q (node), col = r (out ch within tile t)  [m89-verified]
        #pragma unroll
        for (int q = 0; q < 4; ++q)
            h[(size_t)(m0 + half * 4 + q) * D + t * 16 + r] = f2bf(cacc[q]);
    }
}

// ---- emb[i] = relu(base[i] + sum_{j in N(i)} h[csr_col[j]]) ; 16 edges in flight ----
template<int LAST>
__global__ __launch_bounds__(256) void k_pull(
        const int* __restrict__ end_ptr, const int* __restrict__ cnt,
        const int* __restrict__ csr_col, const unsigned short* __restrict__ h,
        const float* __restrict__ base,
        unsigned short* __restrict__ out_bf, float* __restrict__ out_f32) {
    int tid = threadIdx.x;
    int wave = tid >> 6, lane = tid & 63;
    int g = lane >> 3, l = lane & 7;   // group g: edges start+g, +8,...; lane-in-group: ch l*8..+7
    for (int it = blockIdx.x; it < NN / 4; it += gridDim.x) {
        int node = it * 4 + wave;
        int end = end_ptr[node];
        int start = end - cnt[node];
        float acc[8] = {0.f, 0.f, 0.f, 0.f, 0.f, 0.f, 0.f, 0.f};
        int j = start + g;
        for (; j + 8 < end; j += 16) {     // 2 edges per group in flight
            int c0 = csr_col[j];
            int c1 = csr_col[j + 8];
            ushort8v v0 = *((const ushort8v*)(h + (size_t)c0 * D) + l);
            ushort8v v1 = *((const ushort8v*)(h + (size_t)c1 * D) + l);
            #pragma unroll
            for (int u = 0; u < 8; ++u) acc[u] += bf2f(v0[u]) + bf2f(v1[u]);
        }
        if (j < end) {
            int c0 = csr_col[j];
            ushort8v v0 = *((const ushort8v*)(h + (size_t)c0 * D) + l);
            #pragma unroll
            for (int u = 0; u < 8; ++u) acc[u] += bf2f(v0[u]);
        }
        // butterfly over the 8 groups (lane bits 3,4,5)
        #pragma unroll
        for (int m = 8; m < 64; m <<= 1) {
            #pragma unroll
            for (int u = 0; u < 8; ++u) acc[u] += __shfl_xor(acc[u], m);
        }
        if (g < 2) {     // 16 lanes store one coalesced row
            int off = l * 8 + g * 4;
            f32x4 b = *(const f32x4*)(base + (size_t)node * D + off);
            float rr[4];
            #pragma unroll
            for (int u = 0; u < 4; ++u) {
                float a = (g == 1) ? acc[u + 4] : acc[u];
                rr[u] = fmaxf(b[u] + a, 0.f);
            }
            if (LAST) {
                f32x4 o4 = {rr[0], rr[1], rr[2], rr[3]};
                *(f32x4*)(out_f32 + (size_t)node * D + off) = o4;
            } else {
                ushort4v o4;
                #pragma unroll
                for (int u = 0; u < 4; ++u) o4[u] = f2bf(rr[u]);
                *(ushort4v*)(out_bf + (size_t)node * D + off) = o4;
            }
        }
    }
}

extern "C" void kernel_launch(void* const* d_in, const int* in_sizes, int n_in,
                              void* d_out, int out_size, void* d_ws, size_t ws_size,
                              hipStream_t stream) {
    const float* Xv = (const float*)d_in[0];
    const int*   ei = (const int*)d_in[1];
    const float* W1 = (const float*)d_in[2];
    const float* W2 = (const float*)d_in[3];
    const float* W3 = (const float*)d_in[4];
    const float* W4 = (const float*)d_in[5];

    char* ws = (char*)d_ws;
    size_t off = 0;
    float* base = (float*)(ws + off);                  off += (size_t)NN * D * 4;  // 25.6 MB
    unsigned short* h = (unsigned short*)(ws + off);   off += (size_t)NN * D * 2;  // 12.8 MB
    int* csr_col = (int*)(ws + off);                   off += (size_t)NE * 4;      // 6.4 MB
    int* cnt     = (int*)(ws + off);                   off += (size_t)NN * 4;
    int* end_g   = (int*)(ws + off);                   off += (size_t)NN * 4;
    int* ghist   = (int*)(ws + off);                   off += NBKT * 4;
    int* bbase   = (int*)(ws + off);                   off += (NBKT + 1) * 4;
    int* bcur    = (int*)(ws + off);                   off += NBKT * 4;
    float* cvec  = (float*)(ws + off);                 off += D * 4;
    unsigned short* w2b = (unsigned short*)(ws + off); off += D * D * 2;

    // aliases: sorted (6.4 MB) lives in h's space (dead before k_h writes h);
    // intermediate bf16 emb lives in d_out's bytes (final step overwrites with fp32).
    unsigned* sorted = (unsigned*)h;
    unsigned short* emb_bf = (unsigned short*)d_out;
    float* emb_f32 = (float*)d_out;

    const int* row = ei;
    const int* col = ei + NE;

    // ---- CSR build: two-level multisplit (dense writes, no random write-through) ----
    hipMemsetAsync(ghist, 0, NBKT * sizeof(int), stream);
    k_hist<<<NBLK_E, 256, 0, stream>>>(row, ghist);
    k_bscan<<<1, 256, 0, stream>>>(ghist, bbase, bcur);
    k_bucket<<<NBLK_E, 256, 0, stream>>>(row, col, bcur, sorted);
    k_fine<<<NBKT, 256, 0, stream>>>(sorted, bbase, csr_col, cnt, end_g);

    // ---- base, emb1 = relu(base) ----
    k_cvec<<<1, 64, 0, stream>>>(W3, W4, cvec);
    k_w2bf<<<16, 256, 0, stream>>>(W2, w2b);
    k_base<<<NN / 4, 256, 0, stream>>>(Xv, W1, cnt, cvec, base, emb_bf);

    // ---- 3 remaining message-passing steps ----
    for (int t = 0; t < 3; ++t) {
        k_h<<<(NN / 16 + 3) / 4, 256, 0, stream>>>(emb_bf, w2b, h);
        if (t < 2)
            k_pull<0><<<2048, 256, 0, stream>>>(end_g, cnt, csr_col, h, base, emb_bf, nullptr);
        else
            k_pull<1><<<2048, 256, 0, stream>>>(end_g, cnt, csr_col, h, base, nullptr, emb_f32);
    }
}

// Round 5
// 230.664 us; speedup vs baseline: 5.8233x; 1.2259x over previous
//
#include <hip/hip_runtime.h>

#define NN 100000
#define NE 1600000
#define D  64
#define BSH 8                                  // bucket shift: 256 nodes/bucket
#define NBKT ((NN + 255) >> BSH)               // 391
#define NBLK_E ((NE / 4 + 1023) / 1024)        // 391 blocks, 1024 int4s each
#define H_SCALE 256.0f
#define H_ISCALE 0.00390625f

typedef __attribute__((ext_vector_type(8))) short short8v;
typedef __attribute__((ext_vector_type(8))) unsigned short ushort8v;
typedef __attribute__((ext_vector_type(4))) unsigned short ushort4v;
typedef __attribute__((ext_vector_type(4))) float f32x4;
typedef __attribute__((ext_vector_type(2))) float f32x2;

__device__ __forceinline__ float bf2f(unsigned short x) {
    return __uint_as_float(((unsigned)x) << 16);
}
__device__ __forceinline__ unsigned short f2bf(float f) {  // RNE
    unsigned u = __float_as_uint(f);
    return (unsigned short)((u + 0x7fff + ((u >> 16) & 1)) >> 16);
}

// ---- pass A: global bucket histogram (LDS-staged) ----
__global__ __launch_bounds__(256) void k_hist(const int* __restrict__ row,
                                              int* __restrict__ ghist) {
    __shared__ int h[NBKT];
    int tid = threadIdx.x;
    for (int i = tid; i < NBKT; i += 256) h[i] = 0;
    __syncthreads();
    int base4 = blockIdx.x * 1024;
    #pragma unroll
    for (int k = 0; k < 4; ++k) {
        int i4 = base4 + k * 256 + tid;
        if (i4 < NE / 4) {
            int4 r = ((const int4*)row)[i4];
            atomicAdd(&h[r.x >> BSH], 1);
            atomicAdd(&h[r.y >> BSH], 1);
            atomicAdd(&h[r.z >> BSH], 1);
            atomicAdd(&h[r.w >> BSH], 1);
        }
    }
    __syncthreads();
    for (int i = tid; i < NBKT; i += 256) if (h[i]) atomicAdd(&ghist[i], h[i]);
}

// ---- pass B: exclusive scan of 391 bucket counts (1 block) ----
__global__ __launch_bounds__(256) void k_bscan(const int* __restrict__ ghist,
                                               int* __restrict__ bbase,
                                               int* __restrict__ bcur) {
    __shared__ int sc[2][512];
    int t = threadIdx.x;
    int cur = 0;
    #pragma unroll
    for (int k = 0; k < 2; ++k) {
        int i = t + k * 256;
        sc[0][i] = (i < NBKT) ? ghist[i] : 0;
    }
    __syncthreads();
    for (int s = 1; s < 512; s <<= 1) {
        #pragma unroll
        for (int k = 0; k < 2; ++k) {
            int i = t + k * 256;
            sc[cur ^ 1][i] = sc[cur][i] + ((i >= s) ? sc[cur][i - s] : 0);
        }
        cur ^= 1;
        __syncthreads();
    }
    #pragma unroll
    for (int k = 0; k < 2; ++k) {
        int i = t + k * 256;
        if (i < NBKT) {
            int b = (i == 0) ? 0 : sc[cur][i - 1];
            bbase[i] = b;
            bcur[i] = b;
        } else if (i == NBKT) {
            bbase[NBKT] = sc[cur][NBKT - 1];   // = NE
        }
    }
}

// ---- pass C: bucket-sort edges into packed u32 (lrow<<17 | col) ----
__global__ __launch_bounds__(256) void k_bucket(const int* __restrict__ row,
                                                const int* __restrict__ col,
                                                int* __restrict__ bcur,
                                                unsigned* __restrict__ sorted) {
    __shared__ int hist[NBKT];
    __shared__ int bbase_s[NBKT];
    int tid = threadIdx.x;
    for (int i = tid; i < NBKT; i += 256) hist[i] = 0;
    __syncthreads();
    int base4 = blockIdx.x * 1024;
    int4 r4[4], c4[4];
    int rank[16];
    bool valid[4];
    #pragma unroll
    for (int k = 0; k < 4; ++k) {
        int i4 = base4 + k * 256 + tid;
        valid[k] = (i4 < NE / 4);
        if (valid[k]) {
            r4[k] = ((const int4*)row)[i4];
            c4[k] = ((const int4*)col)[i4];
            rank[k * 4 + 0] = atomicAdd(&hist[r4[k].x >> BSH], 1);
            rank[k * 4 + 1] = atomicAdd(&hist[r4[k].y >> BSH], 1);
            rank[k * 4 + 2] = atomicAdd(&hist[r4[k].z >> BSH], 1);
            rank[k * 4 + 3] = atomicAdd(&hist[r4[k].w >> BSH], 1);
        }
    }
    __syncthreads();
    for (int i = tid; i < NBKT; i += 256)
        bbase_s[i] = hist[i] ? atomicAdd(&bcur[i], hist[i]) : 0;
    __syncthreads();
    #pragma unroll
    for (int k = 0; k < 4; ++k) {
        if (valid[k]) {
            int rr[4] = {r4[k].x, r4[k].y, r4[k].z, r4[k].w};
            int cc[4] = {c4[k].x, c4[k].y, c4[k].z, c4[k].w};
            #pragma unroll
            for (int j = 0; j < 4; ++j) {
                int b = rr[j] >> BSH;
                unsigned pk = ((unsigned)(rr[j] & 255) << 17) | (unsigned)cc[j];
                sorted[bbase_s[b] + rank[k * 4 + j]] = pk;
            }
        }
    }
}

// ---- pass D: per-bucket fine CSR (LDS count -> scan -> scatter) ----
__global__ __launch_bounds__(256) void k_fine(const unsigned* __restrict__ sorted,
                                              const int* __restrict__ bbase,
                                              int* __restrict__ csr_col,
                                              int* __restrict__ cnt_g,
                                              int* __restrict__ end_g) {
    __shared__ int cnt_s[256];
    __shared__ int cur_s[256];
    __shared__ int sc[2][256];
    int b = blockIdx.x;
    int tid = threadIdx.x;
    int s0 = bbase[b], e0 = bbase[b + 1];
    cnt_s[tid] = 0;
    __syncthreads();
    for (int i = s0 + tid; i < e0; i += 256)
        atomicAdd(&cnt_s[sorted[i] >> 17], 1);
    __syncthreads();
    int cur = 0;
    sc[0][tid] = cnt_s[tid];
    __syncthreads();
    for (int s = 1; s < 256; s <<= 1) {
        sc[cur ^ 1][tid] = sc[cur][tid] + ((tid >= s) ? sc[cur][tid - s] : 0);
        cur ^= 1;
        __syncthreads();
    }
    int incl = sc[cur][tid];
    cur_s[tid] = incl - cnt_s[tid];           // exclusive offset
    int nb = NN - b * 256;
    nb = nb > 256 ? 256 : nb;
    if (tid < nb) {
        int node = b * 256 + tid;
        cnt_g[node] = cnt_s[tid];
        end_g[node] = s0 + incl;
    }
    __syncthreads();
    for (int i = s0 + tid; i < e0; i += 256) {
        unsigned u = sorted[i];
        int p = atomicAdd(&cur_s[u >> 17], 1);
        csr_col[s0 + p] = (int)(u & 0x1FFFFu);
    }
}

// ---- c[o] = sum_k W3[o][k] * relu(W4[k]) ----
__global__ void k_cvec(const float* __restrict__ W3, const float* __restrict__ W4,
                       float* __restrict__ c) {
    int o = threadIdx.x;  // 64 threads
    float s = 0.f;
    for (int k = 0; k < D; ++k) {
        float w4 = W4[k];
        s += W3[o * D + k] * (w4 > 0.f ? w4 : 0.f);
    }
    c[o] = s;
}

// ---- W1, W2 fp32 -> bf16 ----
__global__ void k_wprep(const float* __restrict__ W1, const float* __restrict__ W2,
                        unsigned short* __restrict__ w1b, unsigned short* __restrict__ w2b) {
    int i = blockIdx.x * 256 + threadIdx.x;
    if (i < D * D) {
        w1b[i] = f2bf(W1[i]);
        w2b[i] = f2bf(W2[i]);
    }
}

// ---- base = Xv@W1.T + deg*c (fp32) via MFMA; emb_bf = relu(base) bf16 ----
__global__ __launch_bounds__(256) void k_base(
        const float* __restrict__ Xv, const unsigned short* __restrict__ w1b,
        const int* __restrict__ cnt, const float* __restrict__ cvec,
        float* __restrict__ base, unsigned short* __restrict__ emb_bf) {
    int wid = blockIdx.x * 4 + (threadIdx.x >> 6);
    int lane = threadIdx.x & 63;
    int m0 = wid * 16;
    if (m0 >= NN) return;
    int r = lane & 15, half = lane >> 4;
    const float* arow = Xv + (size_t)(m0 + r) * D + half * 8;
    f32x4 xa = *(const f32x4*)(arow);
    f32x4 xb = *(const f32x4*)(arow + 4);
    f32x4 xc = *(const f32x4*)(arow + 32);
    f32x4 xd = *(const f32x4*)(arow + 36);
    short8v a0, a1;
    #pragma unroll
    for (int j = 0; j < 4; ++j) {
        a0[j]     = (short)f2bf(xa[j]);
        a0[j + 4] = (short)f2bf(xb[j]);
        a1[j]     = (short)f2bf(xc[j]);
        a1[j + 4] = (short)f2bf(xd[j]);
    }
    int4 c4 = *(const int4*)(cnt + m0 + half * 4);    // deg of the 4 C-rows this lane holds
    float dg[4] = {(float)c4.x, (float)c4.y, (float)c4.z, (float)c4.w};
    #pragma unroll
    for (int t = 0; t < 4; ++t) {
        short8v b0 = *(const short8v*)(w1b + (size_t)(t * 16 + r) * D + half * 8);
        short8v b1 = *(const short8v*)(w1b + (size_t)(t * 16 + r) * D + 32 + half * 8);
        f32x4 cacc = {0.f, 0.f, 0.f, 0.f};
        cacc = __builtin_amdgcn_mfma_f32_16x16x32_bf16(a0, b0, cacc, 0, 0, 0);
        cacc = __builtin_amdgcn_mfma_f32_16x16x32_bf16(a1, b1, cacc, 0, 0, 0);
        float cv = cvec[t * 16 + r];
        #pragma unroll
        for (int q = 0; q < 4; ++q) {
            float s = cacc[q] + dg[q] * cv;
            size_t idx = (size_t)(m0 + half * 4 + q) * D + t * 16 + r;
            base[idx] = s;
            emb_bf[idx] = f2bf(s > 0.f ? s : 0.f);
        }
    }
}

// ---- h8 = fp8_e4m3( (emb_bf @ W2bf.T) * H_SCALE ) via MFMA, 16 nodes/wave ----
__global__ __launch_bounds__(256) void k_h(
        const unsigned short* __restrict__ emb_bf, const unsigned short* __restrict__ w2b,
        unsigned char* __restrict__ h8) {
    int wid = blockIdx.x * 4 + (threadIdx.x >> 6);
    int lane = threadIdx.x & 63;
    int m0 = wid * 16;
    if (m0 >= NN) return;
    int r = lane & 15, half = lane >> 4;
    const unsigned short* arow = emb_bf + (size_t)(m0 + r) * D + half * 8;
    short8v a0 = *(const short8v*)(arow);
    short8v a1 = *(const short8v*)(arow + 32);
    #pragma unroll
    for (int t = 0; t < 4; ++t) {
        short8v b0 = *(const short8v*)(w2b + (size_t)(t * 16 + r) * D + half * 8);
        short8v b1 = *(const short8v*)(w2b + (size_t)(t * 16 + r) * D + 32 + half * 8);
        f32x4 cacc = {0.f, 0.f, 0.f, 0.f};
        cacc = __builtin_amdgcn_mfma_f32_16x16x32_bf16(a0, b0, cacc, 0, 0, 0);
        cacc = __builtin_amdgcn_mfma_f32_16x16x32_bf16(a1, b1, cacc, 0, 0, 0);
        #pragma unroll
        for (int q = 0; q < 4; ++q) {
            int pk = __builtin_amdgcn_cvt_pk_fp8_f32(cacc[q] * H_SCALE, 0.f, 0, false);
            h8[(size_t)(m0 + half * 4 + q) * D + t * 16 + r] = (unsigned char)(pk & 0xff);
        }
    }
}

// ---- emb[i] = relu(base[i] + (1/S) * sum_{j in N(i)} h8[csr_col[j]]) ----
template<int LAST>
__global__ __launch_bounds__(256) void k_pull(
        const int* __restrict__ end_ptr, const int* __restrict__ cnt,
        const int* __restrict__ csr_col, const unsigned char* __restrict__ h8,
        const float* __restrict__ base,
        unsigned short* __restrict__ out_bf, float* __restrict__ out_f32) {
    int tid = threadIdx.x;
    int wave = tid >> 6, lane = tid & 63;
    int g = lane >> 3, l = lane & 7;   // group g: edges start+g, +8,...; lane: ch l*8..+7
    for (int it = blockIdx.x; it < NN / 4; it += gridDim.x) {
        int node = it * 4 + wave;
        int end = end_ptr[node];
        int start = end - cnt[node];
        float acc[8] = {0.f, 0.f, 0.f, 0.f, 0.f, 0.f, 0.f, 0.f};
        int j = start + g;
        for (; j + 8 < end; j += 16) {     // 2 edges per group in flight
            int c0 = csr_col[j];
            int c1 = csr_col[j + 8];
            uint2 v0 = *((const uint2*)(h8 + (size_t)c0 * D) + l);   // 8 fp8
            uint2 v1 = *((const uint2*)(h8 + (size_t)c1 * D) + l);
            f32x2 f;
            f = __builtin_amdgcn_cvt_pk_f32_fp8(v0.x, false); acc[0] += f.x; acc[1] += f.y;
            f = __builtin_amdgcn_cvt_pk_f32_fp8(v0.x, true);  acc[2] += f.x; acc[3] += f.y;
            f = __builtin_amdgcn_cvt_pk_f32_fp8(v0.y, false); acc[4] += f.x; acc[5] += f.y;
            f = __builtin_amdgcn_cvt_pk_f32_fp8(v0.y, true);  acc[6] += f.x; acc[7] += f.y;
            f = __builtin_amdgcn_cvt_pk_f32_fp8(v1.x, false); acc[0] += f.x; acc[1] += f.y;
            f = __builtin_amdgcn_cvt_pk_f32_fp8(v1.x, true);  acc[2] += f.x; acc[3] += f.y;
            f = __builtin_amdgcn_cvt_pk_f32_fp8(v1.y, false); acc[4] += f.x; acc[5] += f.y;
            f = __builtin_amdgcn_cvt_pk_f32_fp8(v1.y, true);  acc[6] += f.x; acc[7] += f.y;
        }
        if (j < end) {
            int c0 = csr_col[j];
            uint2 v0 = *((const uint2*)(h8 + (size_t)c0 * D) + l);
            f32x2 f;
            f = __builtin_amdgcn_cvt_pk_f32_fp8(v0.x, false); acc[0] += f.x; acc[1] += f.y;
            f = __builtin_amdgcn_cvt_pk_f32_fp8(v0.x, true);  acc[2] += f.x; acc[3] += f.y;
            f = __builtin_amdgcn_cvt_pk_f32_fp8(v0.y, false); acc[4] += f.x; acc[5] += f.y;
            f = __builtin_amdgcn_cvt_pk_f32_fp8(v0.y, true);  acc[6] += f.x; acc[7] += f.y;
        }
        // butterfly over the 8 groups (lane bits 3,4,5)
        #pragma unroll
        for (int m = 8; m < 64; m <<= 1) {
            #pragma unroll
            for (int u = 0; u < 8; ++u) acc[u] += __shfl_xor(acc[u], m);
        }
        if (g < 2) {     // 16 lanes store one coalesced row
            int off = l * 8 + g * 4;
            f32x4 b = *(const f32x4*)(base + (size_t)node * D + off);
            float rr[4];
            #pragma unroll
            for (int u = 0; u < 4; ++u) {
                float a = (g == 1) ? acc[u + 4] : acc[u];
                rr[u] = fmaxf(fmaf(a, H_ISCALE, b[u]), 0.f);
            }
            if (LAST) {
                f32x4 o4 = {rr[0], rr[1], rr[2], rr[3]};
                *(f32x4*)(out_f32 + (size_t)node * D + off) = o4;
            } else {
                ushort4v o4;
                #pragma unroll
                for (int u = 0; u < 4; ++u) o4[u] = f2bf(rr[u]);
                *(ushort4v*)(out_bf + (size_t)node * D + off) = o4;
            }
        }
    }
}

extern "C" void kernel_launch(void* const* d_in, const int* in_sizes, int n_in,
                              void* d_out, int out_size, void* d_ws, size_t ws_size,
                              hipStream_t stream) {
    const float* Xv = (const float*)d_in[0];
    const int*   ei = (const int*)d_in[1];
    const float* W1 = (const float*)d_in[2];
    const float* W2 = (const float*)d_in[3];
    const float* W3 = (const float*)d_in[4];
    const float* W4 = (const float*)d_in[5];

    char* ws = (char*)d_ws;
    size_t off = 0;
    float* base = (float*)(ws + off);                  off += (size_t)NN * D * 4;  // 25.6 MB
    unsigned char* h8 = (unsigned char*)(ws + off);    off += (size_t)NN * D;      // 6.4 MB
    int* csr_col = (int*)(ws + off);                   off += (size_t)NE * 4;      // 6.4 MB
    int* cnt     = (int*)(ws + off);                   off += (size_t)NN * 4;
    int* end_g   = (int*)(ws + off);                   off += (size_t)NN * 4;
    int* ghist   = (int*)(ws + off);                   off += NBKT * 4;
    int* bbase   = (int*)(ws + off);                   off += (NBKT + 1) * 4;
    int* bcur    = (int*)(ws + off);                   off += NBKT * 4;
    float* cvec  = (float*)(ws + off);                 off += D * 4;
    unsigned short* w1b = (unsigned short*)(ws + off); off += D * D * 2;
    unsigned short* w2b = (unsigned short*)(ws + off); off += D * D * 2;
    unsigned* sorted = (unsigned*)(ws + off);          off += (size_t)NE * 4;      // 6.4 MB

    // intermediate bf16 emb lives in d_out's bytes (final step overwrites with fp32)
    unsigned short* emb_bf = (unsigned short*)d_out;
    float* emb_f32 = (float*)d_out;

    const int* row = ei;
    const int* col = ei + NE;

    // ---- CSR build: two-level multisplit (dense writes) ----
    hipMemsetAsync(ghist, 0, NBKT * sizeof(int), stream);
    k_hist<<<NBLK_E, 256, 0, stream>>>(row, ghist);
    k_bscan<<<1, 256, 0, stream>>>(ghist, bbase, bcur);
    k_bucket<<<NBLK_E, 256, 0, stream>>>(row, col, bcur, sorted);
    k_fine<<<NBKT, 256, 0, stream>>>(sorted, bbase, csr_col, cnt, end_g);

    // ---- weights prep + base, emb1 = relu(base) ----
    k_cvec<<<1, 64, 0, stream>>>(W3, W4, cvec);
    k_wprep<<<16, 256, 0, stream>>>(W1, W2, w1b, w2b);
    k_base<<<(NN / 16 + 3) / 4, 256, 0, stream>>>(Xv, w1b, cnt, cvec, base, emb_bf);

    // ---- 3 remaining message-passing steps ----
    for (int t = 0; t < 3; ++t) {
        k_h<<<(NN / 16 + 3) / 4, 256, 0, stream>>>(emb_bf, w2b, h8);
        if (t < 2)
            k_pull<0><<<2048, 256, 0, stream>>>(end_g, cnt, csr_col, h8, base, emb_bf, nullptr);
        else
            k_pull<1><<<2048, 256, 0, stream>>>(end_g, cnt, csr_col, h8, base, nullptr, emb_f32);
    }
}

// Round 6
// 227.296 us; speedup vs baseline: 5.9095x; 1.0148x over previous
//
#include <hip/hip_runtime.h>

#define NN 100000
#define NE 1600000
#define D  64
#define BSH 8                                  // bucket shift: 256 nodes/bucket
#define NBKT ((NN + 255) >> BSH)               // 391
#define NBLK_E ((NE / 4 + 1023) / 1024)        // 391 blocks, 1024 int4s each
#define H_SCALE 256.0f
#define H_ISCALE 0.00390625f

typedef __attribute__((ext_vector_type(8))) short short8v;
typedef __attribute__((ext_vector_type(8))) unsigned short ushort8v;
typedef __attribute__((ext_vector_type(4))) unsigned short ushort4v;
typedef __attribute__((ext_vector_type(4))) float f32x4;
typedef __attribute__((ext_vector_type(2))) float f32x2;

__device__ __forceinline__ float bf2f(unsigned short x) {
    return __uint_as_float(((unsigned)x) << 16);
}
__device__ __forceinline__ unsigned short f2bf(float f) {  // RNE
    unsigned u = __float_as_uint(f);
    return (unsigned short)((u + 0x7fff + ((u >> 16) & 1)) >> 16);
}

// ---- zero ghist (replaces hipMemsetAsync: graph memset node cost ~43us) ----
__global__ void k_zero(int* __restrict__ g) {
    int i = blockIdx.x * 256 + threadIdx.x;
    if (i < NBKT) g[i] = 0;
}

// ---- pass A: global bucket histogram (LDS-staged) ----
__global__ __launch_bounds__(256) void k_hist(const int* __restrict__ row,
                                              int* __restrict__ ghist) {
    __shared__ int h[NBKT];
    int tid = threadIdx.x;
    for (int i = tid; i < NBKT; i += 256) h[i] = 0;
    __syncthreads();
    int base4 = blockIdx.x * 1024;
    #pragma unroll
    for (int k = 0; k < 4; ++k) {
        int i4 = base4 + k * 256 + tid;
        if (i4 < NE / 4) {
            int4 r = ((const int4*)row)[i4];
            atomicAdd(&h[r.x >> BSH], 1);
            atomicAdd(&h[r.y >> BSH], 1);
            atomicAdd(&h[r.z >> BSH], 1);
            atomicAdd(&h[r.w >> BSH], 1);
        }
    }
    __syncthreads();
    for (int i = tid; i < NBKT; i += 256) if (h[i]) atomicAdd(&ghist[i], h[i]);
}

// ---- pass B: exclusive scan of 391 bucket counts (1 block) ----
__global__ __launch_bounds__(256) void k_bscan(const int* __restrict__ ghist,
                                               int* __restrict__ bbase,
                                               int* __restrict__ bcur) {
    __shared__ int sc[2][512];
    int t = threadIdx.x;
    int cur = 0;
    #pragma unroll
    for (int k = 0; k < 2; ++k) {
        int i = t + k * 256;
        sc[0][i] = (i < NBKT) ? ghist[i] : 0;
    }
    __syncthreads();
    for (int s = 1; s < 512; s <<= 1) {
        #pragma unroll
        for (int k = 0; k < 2; ++k) {
            int i = t + k * 256;
            sc[cur ^ 1][i] = sc[cur][i] + ((i >= s) ? sc[cur][i - s] : 0);
        }
        cur ^= 1;
        __syncthreads();
    }
    #pragma unroll
    for (int k = 0; k < 2; ++k) {
        int i = t + k * 256;
        if (i < NBKT) {
            int b = (i == 0) ? 0 : sc[cur][i - 1];
            bbase[i] = b;
            bcur[i] = b;
        } else if (i == NBKT) {
            bbase[NBKT] = sc[cur][NBKT - 1];   // = NE
        }
    }
}

// ---- pass C: bucket-sort edges into packed u32 (lrow<<17 | col) ----
__global__ __launch_bounds__(256) void k_bucket(const int* __restrict__ row,
                                                const int* __restrict__ col,
                                                int* __restrict__ bcur,
                                                unsigned* __restrict__ sorted) {
    __shared__ int hist[NBKT];
    __shared__ int bbase_s[NBKT];
    int tid = threadIdx.x;
    for (int i = tid; i < NBKT; i += 256) hist[i] = 0;
    __syncthreads();
    int base4 = blockIdx.x * 1024;
    int4 r4[4], c4[4];
    int rank[16];
    bool valid[4];
    #pragma unroll
    for (int k = 0; k < 4; ++k) {
        int i4 = base4 + k * 256 + tid;
        valid[k] = (i4 < NE / 4);
        if (valid[k]) {
            r4[k] = ((const int4*)row)[i4];
            c4[k] = ((const int4*)col)[i4];
            rank[k * 4 + 0] = atomicAdd(&hist[r4[k].x >> BSH], 1);
            rank[k * 4 + 1] = atomicAdd(&hist[r4[k].y >> BSH], 1);
            rank[k * 4 + 2] = atomicAdd(&hist[r4[k].z >> BSH], 1);
            rank[k * 4 + 3] = atomicAdd(&hist[r4[k].w >> BSH], 1);
        }
    }
    __syncthreads();
    for (int i = tid; i < NBKT; i += 256)
        bbase_s[i] = hist[i] ? atomicAdd(&bcur[i], hist[i]) : 0;
    __syncthreads();
    #pragma unroll
    for (int k = 0; k < 4; ++k) {
        if (valid[k]) {
            int rr[4] = {r4[k].x, r4[k].y, r4[k].z, r4[k].w};
            int cc[4] = {c4[k].x, c4[k].y, c4[k].z, c4[k].w};
            #pragma unroll
            for (int j = 0; j < 4; ++j) {
                int b = rr[j] >> BSH;
                unsigned pk = ((unsigned)(rr[j] & 255) << 17) | (unsigned)cc[j];
                sorted[bbase_s[b] + rank[k * 4 + j]] = pk;
            }
        }
    }
}

// ---- pass D: per-bucket fine CSR (LDS count -> scan -> scatter) ----
__global__ __launch_bounds__(256) void k_fine(const unsigned* __restrict__ sorted,
                                              const int* __restrict__ bbase,
                                              int* __restrict__ csr_col,
                                              int* __restrict__ cnt_g,
                                              int2* __restrict__ se_g) {
    __shared__ int cnt_s[256];
    __shared__ int cur_s[256];
    __shared__ int sc[2][256];
    int b = blockIdx.x;
    int tid = threadIdx.x;
    int s0 = bbase[b], e0 = bbase[b + 1];
    cnt_s[tid] = 0;
    __syncthreads();
    for (int i = s0 + tid; i < e0; i += 256)
        atomicAdd(&cnt_s[sorted[i] >> 17], 1);
    __syncthreads();
    int cur = 0;
    sc[0][tid] = cnt_s[tid];
    __syncthreads();
    for (int s = 1; s < 256; s <<= 1) {
        sc[cur ^ 1][tid] = sc[cur][tid] + ((tid >= s) ? sc[cur][tid - s] : 0);
        cur ^= 1;
        __syncthreads();
    }
    int incl = sc[cur][tid];
    cur_s[tid] = incl - cnt_s[tid];           // exclusive offset
    int nb = NN - b * 256;
    nb = nb > 256 ? 256 : nb;
    if (tid < nb) {
        int node = b * 256 + tid;
        cnt_g[node] = cnt_s[tid];
        se_g[node] = make_int2(s0 + incl - cnt_s[tid], s0 + incl);
    }
    __syncthreads();
    for (int i = s0 + tid; i < e0; i += 256) {
        unsigned u = sorted[i];
        int p = atomicAdd(&cur_s[u >> 17], 1);
        csr_col[s0 + p] = (int)(u & 0x1FFFFu);
    }
}

// ---- c[o] = sum_k W3[o][k] * relu(W4[k]) ----
__global__ void k_cvec(const float* __restrict__ W3, const float* __restrict__ W4,
                       float* __restrict__ c) {
    int o = threadIdx.x;  // 64 threads
    float s = 0.f;
    for (int k = 0; k < D; ++k) {
        float w4 = W4[k];
        s += W3[o * D + k] * (w4 > 0.f ? w4 : 0.f);
    }
    c[o] = s;
}

// ---- W1, W2 fp32 -> bf16 ----
__global__ void k_wprep(const float* __restrict__ W1, const float* __restrict__ W2,
                        unsigned short* __restrict__ w1b, unsigned short* __restrict__ w2b) {
    int i = blockIdx.x * 256 + threadIdx.x;
    if (i < D * D) {
        w1b[i] = f2bf(W1[i]);
        w2b[i] = f2bf(W2[i]);
    }
}

// ---- base_bf = bf16(Xv@W1.T + deg*c) via MFMA; emb_bf = bf16(relu(.)) ----
__global__ __launch_bounds__(256) void k_base(
        const float* __restrict__ Xv, const unsigned short* __restrict__ w1b,
        const int* __restrict__ cnt, const float* __restrict__ cvec,
        unsigned short* __restrict__ base_bf, unsigned short* __restrict__ emb_bf) {
    int wid = blockIdx.x * 4 + (threadIdx.x >> 6);
    int lane = threadIdx.x & 63;
    int m0 = wid * 16;
    if (m0 >= NN) return;
    int r = lane & 15, half = lane >> 4;
    const float* arow = Xv + (size_t)(m0 + r) * D + half * 8;
    f32x4 xa = *(const f32x4*)(arow);
    f32x4 xb = *(const f32x4*)(arow + 4);
    f32x4 xc = *(const f32x4*)(arow + 32);
    f32x4 xd = *(const f32x4*)(arow + 36);
    short8v a0, a1;
    #pragma unroll
    for (int j = 0; j < 4; ++j) {
        a0[j]     = (short)f2bf(xa[j]);
        a0[j + 4] = (short)f2bf(xb[j]);
        a1[j]     = (short)f2bf(xc[j]);
        a1[j + 4] = (short)f2bf(xd[j]);
    }
    int4 c4 = *(const int4*)(cnt + m0 + half * 4);    // deg of the 4 C-rows this lane holds
    float dg[4] = {(float)c4.x, (float)c4.y, (float)c4.z, (float)c4.w};
    #pragma unroll
    for (int t = 0; t < 4; ++t) {
        short8v b0 = *(const short8v*)(w1b + (size_t)(t * 16 + r) * D + half * 8);
        short8v b1 = *(const short8v*)(w1b + (size_t)(t * 16 + r) * D + 32 + half * 8);
        f32x4 cacc = {0.f, 0.f, 0.f, 0.f};
        cacc = __builtin_amdgcn_mfma_f32_16x16x32_bf16(a0, b0, cacc, 0, 0, 0);
        cacc = __builtin_amdgcn_mfma_f32_16x16x32_bf16(a1, b1, cacc, 0, 0, 0);
        float cv = cvec[t * 16 + r];
        #pragma unroll
        for (int q = 0; q < 4; ++q) {
            float s = cacc[q] + dg[q] * cv;
            size_t idx = (size_t)(m0 + half * 4 + q) * D + t * 16 + r;
            base_bf[idx] = f2bf(s);
            emb_bf[idx] = f2bf(s > 0.f ? s : 0.f);
        }
    }
}

// ---- h8 = fp8_e4m3( (emb_bf @ W2bf.T) * H_SCALE ) via MFMA, 16 nodes/wave ----
__global__ __launch_bounds__(256) void k_h(
        const unsigned short* __restrict__ emb_bf, const unsigned short* __restrict__ w2b,
        unsigned char* __restrict__ h8) {
    int wid = blockIdx.x * 4 + (threadIdx.x >> 6);
    int lane = threadIdx.x & 63;
    int m0 = wid * 16;
    if (m0 >= NN) return;
    int r = lane & 15, half = lane >> 4;
    const unsigned short* arow = emb_bf + (size_t)(m0 + r) * D + half * 8;
    short8v a0 = *(const short8v*)(arow);
    short8v a1 = *(const short8v*)(arow + 32);
    #pragma unroll
    for (int t = 0; t < 4; ++t) {
        short8v b0 = *(const short8v*)(w2b + (size_t)(t * 16 + r) * D + half * 8);
        short8v b1 = *(const short8v*)(w2b + (size_t)(t * 16 + r) * D + 32 + half * 8);
        f32x4 cacc = {0.f, 0.f, 0.f, 0.f};
        cacc = __builtin_amdgcn_mfma_f32_16x16x32_bf16(a0, b0, cacc, 0, 0, 0);
        cacc = __builtin_amdgcn_mfma_f32_16x16x32_bf16(a1, b1, cacc, 0, 0, 0);
        #pragma unroll
        for (int q = 0; q < 4; ++q) {
            int pk = __builtin_amdgcn_cvt_pk_fp8_f32(cacc[q] * H_SCALE, 0.f, 0, false);
            h8[(size_t)(m0 + half * 4 + q) * D + t * 16 + r] = (unsigned char)(pk & 0xff);
        }
    }
}

// ---- emb[i] = relu(base[i] + (1/S) * sum_{j in N(i)} h8[csr_col[j]]) ----
template<int LAST>
__global__ __launch_bounds__(256) void k_pull(
        const int2* __restrict__ se_g,
        const int* __restrict__ csr_col, const unsigned char* __restrict__ h8,
        const unsigned short* __restrict__ base_bf,
        unsigned short* __restrict__ out_bf, float* __restrict__ out_f32) {
    int tid = threadIdx.x;
    int wave = tid >> 6, lane = tid & 63;
    int g = lane >> 3, l = lane & 7;   // group g: edges start+g, +8,...; lane: ch l*8..+7
    for (int it = blockIdx.x; it < NN / 4; it += gridDim.x) {
        int node = it * 4 + wave;
        int2 se = se_g[node];
        int start = se.x, end = se.y;
        float acc[8] = {0.f, 0.f, 0.f, 0.f, 0.f, 0.f, 0.f, 0.f};
        int j = start + g;
        for (; j + 8 < end; j += 16) {     // 2 edges per group in flight
            int c0 = csr_col[j];
            int c1 = csr_col[j + 8];
            uint2 v0 = *((const uint2*)(h8 + (size_t)c0 * D) + l);   // 8 fp8
            uint2 v1 = *((const uint2*)(h8 + (size_t)c1 * D) + l);
            f32x2 f;
            f = __builtin_amdgcn_cvt_pk_f32_fp8(v0.x, false); acc[0] += f.x; acc[1] += f.y;
            f = __builtin_amdgcn_cvt_pk_f32_fp8(v0.x, true);  acc[2] += f.x; acc[3] += f.y;
            f = __builtin_amdgcn_cvt_pk_f32_fp8(v0.y, false); acc[4] += f.x; acc[5] += f.y;
            f = __builtin_amdgcn_cvt_pk_f32_fp8(v0.y, true);  acc[6] += f.x; acc[7] += f.y;
            f = __builtin_amdgcn_cvt_pk_f32_fp8(v1.x, false); acc[0] += f.x; acc[1] += f.y;
            f = __builtin_amdgcn_cvt_pk_f32_fp8(v1.x, true);  acc[2] += f.x; acc[3] += f.y;
            f = __builtin_amdgcn_cvt_pk_f32_fp8(v1.y, false); acc[4] += f.x; acc[5] += f.y;
            f = __builtin_amdgcn_cvt_pk_f32_fp8(v1.y, true);  acc[6] += f.x; acc[7] += f.y;
        }
        if (j < end) {
            int c0 = csr_col[j];
            uint2 v0 = *((const uint2*)(h8 + (size_t)c0 * D) + l);
            f32x2 f;
            f = __builtin_amdgcn_cvt_pk_f32_fp8(v0.x, false); acc[0] += f.x; acc[1] += f.y;
            f = __builtin_amdgcn_cvt_pk_f32_fp8(v0.x, true);  acc[2] += f.x; acc[3] += f.y;
            f = __builtin_amdgcn_cvt_pk_f32_fp8(v0.y, false); acc[4] += f.x; acc[5] += f.y;
            f = __builtin_amdgcn_cvt_pk_f32_fp8(v0.y, true);  acc[6] += f.x; acc[7] += f.y;
        }
        // butterfly over the 8 groups (lane bits 3,4,5)
        #pragma unroll
        for (int m = 8; m < 64; m <<= 1) {
            #pragma unroll
            for (int u = 0; u < 8; ++u) acc[u] += __shfl_xor(acc[u], m);
        }
        if (g < 2) {     // 16 lanes store one coalesced row
            int off = l * 8 + g * 4;
            ushort4v b4 = *(const ushort4v*)(base_bf + (size_t)node * D + off);
            float rr[4];
            #pragma unroll
            for (int u = 0; u < 4; ++u) {
                float a = (g == 1) ? acc[u + 4] : acc[u];
                rr[u] = fmaxf(fmaf(a, H_ISCALE, bf2f(b4[u])), 0.f);
            }
            if (LAST) {
                f32x4 o4 = {rr[0], rr[1], rr[2], rr[3]};
                *(f32x4*)(out_f32 + (size_t)node * D + off) = o4;
            } else {
                ushort4v o4;
                #pragma unroll
                for (int u = 0; u < 4; ++u) o4[u] = f2bf(rr[u]);
                *(ushort4v*)(out_bf + (size_t)node * D + off) = o4;
            }
        }
    }
}

extern "C" void kernel_launch(void* const* d_in, const int* in_sizes, int n_in,
                              void* d_out, int out_size, void* d_ws, size_t ws_size,
                              hipStream_t stream) {
    const float* Xv = (const float*)d_in[0];
    const int*   ei = (const int*)d_in[1];
    const float* W1 = (const float*)d_in[2];
    const float* W2 = (const float*)d_in[3];
    const float* W3 = (const float*)d_in[4];
    const float* W4 = (const float*)d_in[5];

    char* ws = (char*)d_ws;
    size_t off = 0;
    unsigned short* base_bf = (unsigned short*)(ws + off); off += (size_t)NN * D * 2; // 12.8 MB
    unsigned char* h8 = (unsigned char*)(ws + off);    off += (size_t)NN * D;      // 6.4 MB
    int* csr_col = (int*)(ws + off);                   off += (size_t)NE * 4;      // 6.4 MB
    int* cnt     = (int*)(ws + off);                   off += (size_t)NN * 4;
    int2* se_g   = (int2*)(ws + off);                  off += (size_t)NN * 8;
    int* ghist   = (int*)(ws + off);                   off += NBKT * 4;
    int* bbase   = (int*)(ws + off);                   off += (NBKT + 1) * 4;
    int* bcur    = (int*)(ws + off);                   off += NBKT * 4;
    float* cvec  = (float*)(ws + off);                 off += D * 4;
    unsigned short* w1b = (unsigned short*)(ws + off); off += D * D * 2;
    unsigned short* w2b = (unsigned short*)(ws + off); off += D * D * 2;
    unsigned* sorted = (unsigned*)(ws + off);          off += (size_t)NE * 4;      // 6.4 MB

    // intermediate bf16 emb lives in d_out's bytes (final step overwrites with fp32)
    unsigned short* emb_bf = (unsigned short*)d_out;
    float* emb_f32 = (float*)d_out;

    const int* row = ei;
    const int* col = ei + NE;

    // ---- CSR build: two-level multisplit (dense writes) ----
    k_zero<<<2, 256, 0, stream>>>(ghist);
    k_hist<<<NBLK_E, 256, 0, stream>>>(row, ghist);
    k_bscan<<<1, 256, 0, stream>>>(ghist, bbase, bcur);
    k_bucket<<<NBLK_E, 256, 0, stream>>>(row, col, bcur, sorted);
    k_fine<<<NBKT, 256, 0, stream>>>(sorted, bbase, csr_col, cnt, se_g);

    // ---- weights prep + base, emb1 = relu(base) ----
    k_cvec<<<1, 64, 0, stream>>>(W3, W4, cvec);
    k_wprep<<<16, 256, 0, stream>>>(W1, W2, w1b, w2b);
    k_base<<<(NN / 16 + 3) / 4, 256, 0, stream>>>(Xv, w1b, cnt, cvec, base_bf, emb_bf);

    // ---- 3 remaining message-passing steps ----
    for (int t = 0; t < 3; ++t) {
        k_h<<<(NN / 16 + 3) / 4, 256, 0, stream>>>(emb_bf, w2b, h8);
        if (t < 2)
            k_pull<0><<<2048, 256, 0, stream>>>(se_g, csr_col, h8, base_bf, emb_bf, nullptr);
        else
            k_pull<1><<<2048, 256, 0, stream>>>(se_g, csr_col, h8, base_bf, nullptr, emb_f32);
    }
}